// Round 5
// baseline (703.820 us; speedup 1.0000x reference)
//
#include <hip/hip_runtime.h>

#define NN 50000
#define EE 1600000
#define HD 256
#define MPAD 50048      // 391 * 128
#define LN_EPS 1e-5f

#define NB 256          // coarse buckets
#define BR 196          // node range per bucket (256*196 = 50176 >= 50048)
#define NBLK 128        // radix count/scatter blocks
#define CH 12500        // edges per block (128*12500 = 1.6M)
#define SL 16           // src slices
#define SSH 12          // src >> 12  (4096 nodes/slice = 2MB bf16 msg slice)
#define FB 3136         // fine bins = BR*SL
#define FBP 3328        // padded to 256*13
#define CF 13           // fine scan chunk per thread

#define AGG_BLOCKS 1024 // co-resident persistent blocks (4/CU at <=128 VGPR)
#define NPW 13          // nodes per wave: 1024*4*13 = 53248 >= 50176

typedef unsigned short ushort_t;
typedef unsigned int uint_t;

using frag_ab = __attribute__((ext_vector_type(8))) short;   // 8 bf16
using frag_cd = __attribute__((ext_vector_type(4))) float;   // 4 f32

__device__ __forceinline__ ushort_t f2bf(float f) {
    uint_t u = __float_as_uint(f);
    uint_t r = (u + 0x7FFFu + ((u >> 16) & 1u)) >> 16;
    return (ushort_t)r;
}
__device__ __forceinline__ float blo(uint_t u) { return __uint_as_float(u << 16); }
__device__ __forceinline__ float bhi(uint_t u) { return __uint_as_float(u & 0xFFFF0000u); }

// ============ radix pass 1: coarse counts (src & dst), no global atomics ======
__global__ __launch_bounds__(256) void radix_count(
    const int* __restrict__ src, const int* __restrict__ dst,
    int* __restrict__ cntD, int* __restrict__ cntS)
{
    __shared__ int hD[NB], hS[NB];
    int t = threadIdx.x, blk = blockIdx.x;
    hD[t] = 0; hS[t] = 0;
    __syncthreads();
    for (int i = t; i < CH; i += 256) {
        int e = blk * CH + i;
        atomicAdd(&hD[dst[e] / BR], 1);
        atomicAdd(&hS[src[e] / BR], 1);
    }
    __syncthreads();
    cntD[t * NBLK + blk] = hD[t];   // bucket-major layout
    cntS[t * NBLK + blk] = hS[t];
}

// ============ radix scan: exclusive scan of 32768 (bucket-major) ==============
__global__ __launch_bounds__(256) void radix_scan(
    const int* __restrict__ cntD, int* __restrict__ scanD, int* __restrict__ bbD,
    const int* __restrict__ cntS, int* __restrict__ scanS, int* __restrict__ bbS)
{
    const int* cnt = (blockIdx.x == 0) ? cntD : cntS;
    int* scn       = (blockIdx.x == 0) ? scanD : scanS;
    int* bb        = (blockIdx.x == 0) ? bbD : bbS;
    int t = threadIdx.x, lane = t & 63, wv = t >> 6;
    int base = t * NBLK;
    int s = 0;
    for (int j = 0; j < NBLK; j++) s += cnt[base + j];
    int sc = s;
    #pragma unroll
    for (int off = 1; off < 64; off <<= 1) {
        int nv = __shfl_up(sc, off);
        if (lane >= off) sc += nv;
    }
    __shared__ int wp[4];
    if (lane == 63) wp[wv] = sc;
    __syncthreads();
    int wb = 0;
    for (int w = 0; w < wv; w++) wb += wp[w];
    int run = wb + sc - s;          // exclusive base for this thread's chunk
    bb[t] = run;                    // chunk start == bucket t start
    for (int j = 0; j < NBLK; j++) { scn[base + j] = run; run += cnt[base + j]; }
    if (t == 255) bb[256] = run;    // total = EE
}

// ============ radix scatter: partition edges by dst (pairs) and src (keys) ====
__global__ __launch_bounds__(256) void radix_scatter(
    const int* __restrict__ src, const int* __restrict__ dst,
    const int* __restrict__ scanD, const int* __restrict__ scanS,
    uint2* __restrict__ dpart, int* __restrict__ spart)
{
    __shared__ int curD[NB], curS[NB];
    int t = threadIdx.x, blk = blockIdx.x;
    curD[t] = scanD[t * NBLK + blk];
    curS[t] = scanS[t * NBLK + blk];
    __syncthreads();
    for (int i = t; i < CH; i += 256) {
        int e = blk * CH + i;
        int sv = src[e], dv = dst[e];
        int pd = atomicAdd(&curD[dv / BR], 1);
        dpart[pd] = make_uint2((uint_t)sv, (uint_t)dv);
        int ps = atomicAdd(&curS[sv / BR], 1);
        spart[ps] = sv;
    }
}

// ============ fine stage (dst): per-bucket CSR sorted by (dst, src-slice) =====
// writes rp16[n*SL + s] global sub-row starts (flat across buckets) + sentinel
__global__ __launch_bounds__(256) void fine_dst(
    const uint2* __restrict__ dpart, const int* __restrict__ bbD,
    int* __restrict__ rp16, int* __restrict__ csr_src)
{
    __shared__ int hist[FBP];
    __shared__ int cur[FBP];
    __shared__ int wp[4];
    int t = threadIdx.x, lane = t & 63, wv = t >> 6;
    int b = blockIdx.x;
    int bb = bbD[b];
    int cnt = bbD[b + 1] - bb;
    int node0 = b * BR;
    #pragma unroll
    for (int j = 0; j < CF; j++) hist[t * CF + j] = 0;
    __syncthreads();
    for (int i = t; i < cnt; i += 256) {
        uint2 p = dpart[bb + i];
        int bin = ((int)p.y - node0) * SL + ((int)p.x >> SSH);
        atomicAdd(&hist[bin], 1);
    }
    __syncthreads();
    // block exclusive scan over FBP bins (chunk CF per thread)
    int vals[CF];
    int s = 0;
    #pragma unroll
    for (int j = 0; j < CF; j++) { vals[j] = hist[t * CF + j]; s += vals[j]; }
    int sc = s;
    #pragma unroll
    for (int off = 1; off < 64; off <<= 1) {
        int nv = __shfl_up(sc, off);
        if (lane >= off) sc += nv;
    }
    if (lane == 63) wp[wv] = sc;
    __syncthreads();
    int wb = 0;
    for (int w = 0; w < wv; w++) wb += wp[w];
    int run = wb + sc - s;
    #pragma unroll
    for (int j = 0; j < CF; j++) {
        int bin = t * CF + j;
        cur[bin] = run;
        if (bin < FB) rp16[b * FB + bin] = bb + run;
        run += vals[j];
    }
    if (b == NB - 1 && t == 0) rp16[NB * FB] = bbD[NB];   // sentinel = EE
    __syncthreads();
    for (int i = t; i < cnt; i += 256) {
        uint2 p = dpart[bb + i];
        int bin = ((int)p.y - node0) * SL + ((int)p.x >> SSH);
        int pos = bb + atomicAdd(&cur[bin], 1);
        csr_src[pos] = (int)p.x;
    }
}

// ============ fine stage (src): per-bucket histogram -> deg_out ===============
__global__ __launch_bounds__(256) void fine_src(
    const int* __restrict__ spart, const int* __restrict__ bbS,
    int* __restrict__ deg_out)
{
    __shared__ int hist[NB];
    int t = threadIdx.x, b = blockIdx.x;
    hist[t] = 0;
    __syncthreads();
    int bb = bbS[b];
    int cnt = bbS[b + 1] - bb;
    int node0 = b * BR;
    for (int i = t; i < cnt; i += 256) atomicAdd(&hist[spart[bb + i] - node0], 1);
    __syncthreads();
    if (t < BR) deg_out[node0 + t] = hist[t];
}

// ---------------- W convert + transpose: Wt[n][k] = bf16(W[k][n]) ----------------
__global__ void wconv(const float* __restrict__ W, ushort_t* __restrict__ Wt) {
    int g = blockIdx.x * 256 + threadIdx.x;
    int k = g >> 8, n = g & 255;
    Wt[n * 256 + k] = f2bf(W[g]);
}

// ---------------- bf16 MFMA GEMM ----------------
__device__ __forceinline__ int swz(int r, int kElem) {
    return ((r * 64 + kElem) * 2) ^ ((r & 7) << 4);
}

template <int A_BF16>
__global__ __launch_bounds__(256) void gemm_mfma(
    const void* __restrict__ Aptr, const ushort_t* __restrict__ Wt,
    const int* __restrict__ deg, ushort_t* __restrict__ Y)
{
    __shared__ __align__(16) ushort_t As[8192];
    __shared__ __align__(16) ushort_t Bs[8192];
    __shared__ float sS[128];

    int t = threadIdx.x;
    int lane = t & 63, wid = t >> 6;
    int wm = wid >> 1, wn = wid & 1;
    int row0 = blockIdx.x * 128;
    int col0 = blockIdx.y * 128;

    if (t < 128) {
        int row = row0 + t;
        int dg = (row < NN) ? deg[row] : 1;
        sS[t] = rsqrtf((float)(dg > 1 ? dg : 1));
    }

    frag_cd acc[4][4];
    #pragma unroll
    for (int m = 0; m < 4; m++)
        #pragma unroll
        for (int n = 0; n < 4; n++) acc[m][n] = (frag_cd)(0.f);

    const float*    Af = (const float*)Aptr;
    const ushort_t* Ab = (const ushort_t*)Aptr;

    for (int k0 = 0; k0 < HD; k0 += 64) {
        __syncthreads();
        #pragma unroll
        for (int i = 0; i < 8; i++) {
            int flat = i * 256 + t;
            int r = flat >> 4;
            int k4 = (flat & 15) * 4;
            int row = row0 + r;
            ushort4 u;
            if constexpr (!A_BF16) {
                float4 v = make_float4(0.f, 0.f, 0.f, 0.f);
                if (row < NN) v = *(const float4*)&Af[(size_t)row * 256 + k0 + k4];
                u.x = f2bf(v.x); u.y = f2bf(v.y); u.z = f2bf(v.z); u.w = f2bf(v.w);
            } else {
                if (row < NN) u = *(const ushort4*)&Ab[(size_t)row * 256 + k0 + k4];
                else u = make_ushort4(0, 0, 0, 0);
            }
            *(ushort4*)((char*)As + swz(r, k4)) = u;
        }
        #pragma unroll
        for (int i = 0; i < 8; i++) {
            int flat = i * 256 + t;
            int nn = flat >> 4;
            int k4 = (flat & 15) * 4;
            ushort4 u = *(const ushort4*)&Wt[(size_t)(col0 + nn) * 256 + k0 + k4];
            *(ushort4*)((char*)Bs + swz(nn, k4)) = u;
        }
        __syncthreads();
        #pragma unroll
        for (int s = 0; s < 2; s++) {
            int kb = s * 32 + ((lane >> 4) * 8);
            frag_ab af[4], bfr[4];
            #pragma unroll
            for (int m = 0; m < 4; m++) {
                int r = wm * 64 + m * 16 + (lane & 15);
                af[m] = *(const frag_ab*)((const char*)As + swz(r, kb));
            }
            #pragma unroll
            for (int n = 0; n < 4; n++) {
                int c = wn * 64 + n * 16 + (lane & 15);
                bfr[n] = *(const frag_ab*)((const char*)Bs + swz(c, kb));
            }
            #pragma unroll
            for (int m = 0; m < 4; m++)
                #pragma unroll
                for (int n = 0; n < 4; n++)
                    acc[m][n] = __builtin_amdgcn_mfma_f32_16x16x32_bf16(
                        af[m], bfr[n], acc[m][n], 0, 0, 0);
        }
    }

    #pragma unroll
    for (int m = 0; m < 4; m++) {
        int rl = wm * 64 + m * 16 + ((lane >> 4) * 4);
        #pragma unroll
        for (int j = 0; j < 4; j++) {
            float sc = sS[rl + j];
            size_t grow = (size_t)(row0 + rl + j);
            #pragma unroll
            for (int n = 0; n < 4; n++) {
                int gcol = col0 + wn * 64 + n * 16 + (lane & 15);
                Y[grow * 256 + gcol] = f2bf(acc[m][n][j] * sc);
            }
        }
    }
}

// ---------------- persistent slice-phased aggregation ----------------
// 1024 co-resident blocks; each wave owns NPW consecutive nodes (reg accum).
// Slice-outer loop: all waves gather from the same 1.6 MB msg slice -> L2-hit.
template <int MODE>
__global__ __launch_bounds__(256, 4) void aggregate_phased(
    const ushort_t* __restrict__ msg, const int* __restrict__ rp16,
    const int* __restrict__ csr_src,
    const float* __restrict__ bias, const float* __restrict__ gamma,
    const float* __restrict__ beta, void* __restrict__ outp)
{
    int lane = threadIdx.x & 63;
    int gw = blockIdx.x * 4 + (threadIdx.x >> 6);
    int n0 = gw * NPW;
    if (n0 >= NB * BR) return;

    float a[NPW][4];
    #pragma unroll
    for (int j = 0; j < NPW; j++) { a[j][0] = a[j][1] = a[j][2] = a[j][3] = 0.f; }
    const uint2* base = (const uint2*)msg;

    for (int s = 0; s < SL; s++) {
        #pragma unroll
        for (int j = 0; j < NPW; j++) {
            int n = n0 + j;
            if (n >= NB * BR) continue;
            int i  = rp16[n * SL + s];
            int en = rp16[n * SL + s + 1];
            for (; i + 4 <= en; i += 4) {
                int i0 = csr_src[i], i1 = csr_src[i + 1];
                int i2 = csr_src[i + 2], i3 = csr_src[i + 3];
                uint2 v0 = base[(size_t)i0 * 64 + lane];
                uint2 v1 = base[(size_t)i1 * 64 + lane];
                uint2 v2 = base[(size_t)i2 * 64 + lane];
                uint2 v3 = base[(size_t)i3 * 64 + lane];
                a[j][0] += blo(v0.x) + blo(v1.x) + blo(v2.x) + blo(v3.x);
                a[j][1] += bhi(v0.x) + bhi(v1.x) + bhi(v2.x) + bhi(v3.x);
                a[j][2] += blo(v0.y) + blo(v1.y) + blo(v2.y) + blo(v3.y);
                a[j][3] += bhi(v0.y) + bhi(v1.y) + bhi(v2.y) + bhi(v3.y);
            }
            if (i + 2 <= en) {
                int i0 = csr_src[i], i1 = csr_src[i + 1];
                uint2 v0 = base[(size_t)i0 * 64 + lane];
                uint2 v1 = base[(size_t)i1 * 64 + lane];
                a[j][0] += blo(v0.x) + blo(v1.x);
                a[j][1] += bhi(v0.x) + bhi(v1.x);
                a[j][2] += blo(v0.y) + blo(v1.y);
                a[j][3] += bhi(v0.y) + bhi(v1.y);
                i += 2;
            }
            if (i < en) {
                int i0 = csr_src[i];
                uint2 v0 = base[(size_t)i0 * 64 + lane];
                a[j][0] += blo(v0.x); a[j][1] += bhi(v0.x);
                a[j][2] += blo(v0.y); a[j][3] += bhi(v0.y);
            }
        }
    }

    // epilogue per node
    float4 b  = ((const float4*)bias)[lane];
    #pragma unroll
    for (int j = 0; j < NPW; j++) {
        int n = n0 + j;
        if (n >= NN) continue;
        int cnt = rp16[n * SL + SL] - rp16[n * SL];
        float scl = rsqrtf((float)(cnt > 1 ? cnt : 1));
        float r0 = a[j][0] * scl + b.x;
        float r1 = a[j][1] * scl + b.y;
        float r2 = a[j][2] * scl + b.z;
        float r3 = a[j][3] * scl + b.w;
        if (MODE == 0) {
            r0 = fmaxf(r0, 0.f); r1 = fmaxf(r1, 0.f);
            r2 = fmaxf(r2, 0.f); r3 = fmaxf(r3, 0.f);
            uint2 o;
            o.x = (uint_t)f2bf(r0) | ((uint_t)f2bf(r1) << 16);
            o.y = (uint_t)f2bf(r2) | ((uint_t)f2bf(r3) << 16);
            ((uint2*)outp)[(size_t)n * 64 + lane] = o;
        } else {
            float s1 = r0 + r1 + r2 + r3;
            #pragma unroll
            for (int off = 1; off < 64; off <<= 1) s1 += __shfl_xor(s1, off);
            float mu = s1 * (1.f / 256.f);
            float d0 = r0 - mu, d1 = r1 - mu, d2 = r2 - mu, d3 = r3 - mu;
            float s2 = d0 * d0 + d1 * d1 + d2 * d2 + d3 * d3;
            #pragma unroll
            for (int off = 1; off < 64; off <<= 1) s2 += __shfl_xor(s2, off);
            float rs = rsqrtf(s2 * (1.f / 256.f) + LN_EPS);
            float4 g  = ((const float4*)gamma)[lane];
            float4 be = ((const float4*)beta)[lane];
            float4 o;
            o.x = d0 * rs * g.x + be.x;
            o.y = d1 * rs * g.y + be.y;
            o.z = d2 * rs * g.z + be.z;
            o.w = d3 * rs * g.w + be.w;
            ((float4*)outp)[(size_t)n * 64 + lane] = o;
        }
    }
}

extern "C" void kernel_launch(void* const* d_in, const int* in_sizes, int n_in,
                              void* d_out, int out_size, void* d_ws, size_t ws_size,
                              hipStream_t stream)
{
    const float* x     = (const float*)d_in[0];
    const float* W1    = (const float*)d_in[1];
    const float* b1    = (const float*)d_in[2];
    const float* W2    = (const float*)d_in[3];
    const float* b2    = (const float*)d_in[4];
    const float* gamma = (const float*)d_in[5];
    const float* beta  = (const float*)d_in[6];
    const int*   src   = (const int*)d_in[7];
    const int*   dst   = (const int*)d_in[8];
    float* out = (float*)d_out;

    // ws layout (~55 MB)
    uint2*    dpart  = (uint2*)d_ws;                         // EE uint2   12.8MB
    ushort_t* msg    = (ushort_t*)(dpart + EE);              // MPAD*256   25.6MB
    int*      csr    = (int*)(msg + (size_t)MPAD * 256);     // EE          6.4MB
    int*      spart  = csr + EE;                             // EE          6.4MB
    int*      rp16   = spart + EE;                           // NB*FB+16    3.2MB
    int*      cntD   = rp16 + NB * FB + 16;
    int*      cntS   = cntD + NB * NBLK;
    int*      scanD  = cntS + NB * NBLK;
    int*      scanS  = scanD + NB * NBLK;
    int*      bbD    = scanS + NB * NBLK;                    // 320 (257 used)
    int*      bbS    = bbD + 320;                            // 320
    int*      degout = bbS + 320;                            // 50176
    ushort_t* Wt1    = (ushort_t*)(degout + NB * BR);        // 65536 bf16
    ushort_t* Wt2    = Wt1 + 65536;                          // 65536 bf16

    ushort_t* h = (ushort_t*)d_out;   // layer-1 activation (bf16) in d_out

    radix_count  <<<NBLK, 256, 0, stream>>>(src, dst, cntD, cntS);
    radix_scan   <<<2, 256, 0, stream>>>(cntD, scanD, bbD, cntS, scanS, bbS);
    radix_scatter<<<NBLK, 256, 0, stream>>>(src, dst, scanD, scanS, dpart, spart);
    fine_dst     <<<NB, 256, 0, stream>>>(dpart, bbD, rp16, csr);
    fine_src     <<<NB, 256, 0, stream>>>(spart, bbS, degout);

    wconv<<<256, 256, 0, stream>>>(W1, Wt1);
    wconv<<<256, 256, 0, stream>>>(W2, Wt2);

    dim3 gg(MPAD / 128, 2);
    gemm_mfma<0><<<gg, 256, 0, stream>>>(x, Wt1, degout, msg);
    aggregate_phased<0><<<AGG_BLOCKS, 256, 0, stream>>>(msg, rp16, csr,
                                                        b1, nullptr, nullptr, h);
    gemm_mfma<1><<<gg, 256, 0, stream>>>(h, Wt2, degout, msg);
    aggregate_phased<1><<<AGG_BLOCKS, 256, 0, stream>>>(msg, rp16, csr,
                                                        b2, gamma, beta, out);
}

// Round 6
// 485.544 us; speedup vs baseline: 1.4495x; 1.4495x over previous
//
#include <hip/hip_runtime.h>

#define NN 50000
#define EE 1600000
#define HD 256
#define MPAD 50048      // 391 * 128
#define LN_EPS 1e-5f

#define NB 256          // coarse buckets
#define BR 196          // node range per bucket (256*196 = 50176 >= 50048)
#define NBLK 128        // radix count/scatter blocks
#define CH 12500        // edges per block (128*12500 = 1.6M)
#define SL 16           // src slices
#define SSH 12          // src >> 12  (4096 nodes/slice = 2MB bf16 msg slice)
#define FB 3136         // fine bins = BR*SL
#define FBP 3328        // padded to 256*13
#define CF 13           // fine scan chunk per thread

typedef unsigned short ushort_t;
typedef unsigned int uint_t;

using frag_ab = __attribute__((ext_vector_type(8))) short;   // 8 bf16
using frag_cd = __attribute__((ext_vector_type(4))) float;   // 4 f32

__device__ __forceinline__ ushort_t f2bf(float f) {
    uint_t u = __float_as_uint(f);
    uint_t r = (u + 0x7FFFu + ((u >> 16) & 1u)) >> 16;
    return (ushort_t)r;
}
__device__ __forceinline__ float blo(uint_t u) { return __uint_as_float(u << 16); }
__device__ __forceinline__ float bhi(uint_t u) { return __uint_as_float(u & 0xFFFF0000u); }

// ============ radix pass 1: coarse counts (src & dst), no global atomics ======
__global__ __launch_bounds__(256) void radix_count(
    const int* __restrict__ src, const int* __restrict__ dst,
    int* __restrict__ cntD, int* __restrict__ cntS)
{
    __shared__ int hD[NB], hS[NB];
    int t = threadIdx.x, blk = blockIdx.x;
    hD[t] = 0; hS[t] = 0;
    __syncthreads();
    for (int i = t; i < CH; i += 256) {
        int e = blk * CH + i;
        atomicAdd(&hD[dst[e] / BR], 1);
        atomicAdd(&hS[src[e] / BR], 1);
    }
    __syncthreads();
    cntD[t * NBLK + blk] = hD[t];   // bucket-major layout
    cntS[t * NBLK + blk] = hS[t];
}

// ============ radix scan: exclusive scan of 32768 (bucket-major) ==============
__global__ __launch_bounds__(256) void radix_scan(
    const int* __restrict__ cntD, int* __restrict__ scanD, int* __restrict__ bbD,
    const int* __restrict__ cntS, int* __restrict__ scanS, int* __restrict__ bbS)
{
    const int* cnt = (blockIdx.x == 0) ? cntD : cntS;
    int* scn       = (blockIdx.x == 0) ? scanD : scanS;
    int* bb        = (blockIdx.x == 0) ? bbD : bbS;
    int t = threadIdx.x, lane = t & 63, wv = t >> 6;
    int base = t * NBLK;
    int s = 0;
    for (int j = 0; j < NBLK; j++) s += cnt[base + j];
    int sc = s;
    #pragma unroll
    for (int off = 1; off < 64; off <<= 1) {
        int nv = __shfl_up(sc, off);
        if (lane >= off) sc += nv;
    }
    __shared__ int wp[4];
    if (lane == 63) wp[wv] = sc;
    __syncthreads();
    int wb = 0;
    for (int w = 0; w < wv; w++) wb += wp[w];
    int run = wb + sc - s;          // exclusive base for this thread's chunk
    bb[t] = run;                    // chunk start == bucket t start
    for (int j = 0; j < NBLK; j++) { scn[base + j] = run; run += cnt[base + j]; }
    if (t == 255) bb[256] = run;    // total = EE
}

// ============ radix scatter: partition edges by dst (pairs) and src (keys) ====
__global__ __launch_bounds__(256) void radix_scatter(
    const int* __restrict__ src, const int* __restrict__ dst,
    const int* __restrict__ scanD, const int* __restrict__ scanS,
    uint2* __restrict__ dpart, int* __restrict__ spart)
{
    __shared__ int curD[NB], curS[NB];
    int t = threadIdx.x, blk = blockIdx.x;
    curD[t] = scanD[t * NBLK + blk];
    curS[t] = scanS[t * NBLK + blk];
    __syncthreads();
    for (int i = t; i < CH; i += 256) {
        int e = blk * CH + i;
        int sv = src[e], dv = dst[e];
        int pd = atomicAdd(&curD[dv / BR], 1);
        dpart[pd] = make_uint2((uint_t)sv, (uint_t)dv);
        int ps = atomicAdd(&curS[sv / BR], 1);
        spart[ps] = sv;
    }
}

// ============ fine stage (dst): per-bucket CSR sorted by (dst, src-slice) =====
__global__ __launch_bounds__(256) void fine_dst(
    const uint2* __restrict__ dpart, const int* __restrict__ bbD,
    int* __restrict__ rp16, int* __restrict__ csr_src)
{
    __shared__ int hist[FBP];
    __shared__ int cur[FBP];
    __shared__ int wp[4];
    int t = threadIdx.x, lane = t & 63, wv = t >> 6;
    int b = blockIdx.x;
    int bb = bbD[b];
    int cnt = bbD[b + 1] - bb;
    int node0 = b * BR;
    #pragma unroll
    for (int j = 0; j < CF; j++) hist[t * CF + j] = 0;
    __syncthreads();
    for (int i = t; i < cnt; i += 256) {
        uint2 p = dpart[bb + i];
        int bin = ((int)p.y - node0) * SL + ((int)p.x >> SSH);
        atomicAdd(&hist[bin], 1);
    }
    __syncthreads();
    int vals[CF];
    int s = 0;
    #pragma unroll
    for (int j = 0; j < CF; j++) { vals[j] = hist[t * CF + j]; s += vals[j]; }
    int sc = s;
    #pragma unroll
    for (int off = 1; off < 64; off <<= 1) {
        int nv = __shfl_up(sc, off);
        if (lane >= off) sc += nv;
    }
    if (lane == 63) wp[wv] = sc;
    __syncthreads();
    int wb = 0;
    for (int w = 0; w < wv; w++) wb += wp[w];
    int run = wb + sc - s;
    #pragma unroll
    for (int j = 0; j < CF; j++) {
        int bin = t * CF + j;
        cur[bin] = run;
        if (bin < FB) rp16[b * FB + bin] = bb + run;
        run += vals[j];
    }
    if (b == NB - 1 && t == 0) rp16[NB * FB] = bbD[NB];   // sentinel = EE
    __syncthreads();
    for (int i = t; i < cnt; i += 256) {
        uint2 p = dpart[bb + i];
        int bin = ((int)p.y - node0) * SL + ((int)p.x >> SSH);
        int pos = bb + atomicAdd(&cur[bin], 1);
        csr_src[pos] = (int)p.x;
    }
}

// ============ fine stage (src): per-bucket histogram -> deg_out ===============
__global__ __launch_bounds__(256) void fine_src(
    const int* __restrict__ spart, const int* __restrict__ bbS,
    int* __restrict__ deg_out)
{
    __shared__ int hist[NB];
    int t = threadIdx.x, b = blockIdx.x;
    hist[t] = 0;
    __syncthreads();
    int bb = bbS[b];
    int cnt = bbS[b + 1] - bb;
    int node0 = b * BR;
    for (int i = t; i < cnt; i += 256) atomicAdd(&hist[spart[bb + i] - node0], 1);
    __syncthreads();
    if (t < BR) deg_out[node0 + t] = hist[t];
}

// ---------------- W convert + transpose: Wt[n][k] = bf16(W[k][n]) ----------------
__global__ void wconv(const float* __restrict__ W, ushort_t* __restrict__ Wt) {
    int g = blockIdx.x * 256 + threadIdx.x;
    int k = g >> 8, n = g & 255;
    Wt[n * 256 + k] = f2bf(W[g]);
}

// ---------------- bf16 MFMA GEMM ----------------
__device__ __forceinline__ int swz(int r, int kElem) {
    return ((r * 64 + kElem) * 2) ^ ((r & 7) << 4);
}

template <int A_BF16>
__global__ __launch_bounds__(256) void gemm_mfma(
    const void* __restrict__ Aptr, const ushort_t* __restrict__ Wt,
    const int* __restrict__ deg, ushort_t* __restrict__ Y)
{
    __shared__ __align__(16) ushort_t As[8192];
    __shared__ __align__(16) ushort_t Bs[8192];
    __shared__ float sS[128];

    int t = threadIdx.x;
    int lane = t & 63, wid = t >> 6;
    int wm = wid >> 1, wn = wid & 1;
    int row0 = blockIdx.x * 128;
    int col0 = blockIdx.y * 128;

    if (t < 128) {
        int row = row0 + t;
        int dg = (row < NN) ? deg[row] : 1;
        sS[t] = rsqrtf((float)(dg > 1 ? dg : 1));
    }

    frag_cd acc[4][4];
    #pragma unroll
    for (int m = 0; m < 4; m++)
        #pragma unroll
        for (int n = 0; n < 4; n++) acc[m][n] = (frag_cd)(0.f);

    const float*    Af = (const float*)Aptr;
    const ushort_t* Ab = (const ushort_t*)Aptr;

    for (int k0 = 0; k0 < HD; k0 += 64) {
        __syncthreads();
        #pragma unroll
        for (int i = 0; i < 8; i++) {
            int flat = i * 256 + t;
            int r = flat >> 4;
            int k4 = (flat & 15) * 4;
            int row = row0 + r;
            ushort4 u;
            if constexpr (!A_BF16) {
                float4 v = make_float4(0.f, 0.f, 0.f, 0.f);
                if (row < NN) v = *(const float4*)&Af[(size_t)row * 256 + k0 + k4];
                u.x = f2bf(v.x); u.y = f2bf(v.y); u.z = f2bf(v.z); u.w = f2bf(v.w);
            } else {
                if (row < NN) u = *(const ushort4*)&Ab[(size_t)row * 256 + k0 + k4];
                else u = make_ushort4(0, 0, 0, 0);
            }
            *(ushort4*)((char*)As + swz(r, k4)) = u;
        }
        #pragma unroll
        for (int i = 0; i < 8; i++) {
            int flat = i * 256 + t;
            int nn = flat >> 4;
            int k4 = (flat & 15) * 4;
            ushort4 u = *(const ushort4*)&Wt[(size_t)(col0 + nn) * 256 + k0 + k4];
            *(ushort4*)((char*)Bs + swz(nn, k4)) = u;
        }
        __syncthreads();
        #pragma unroll
        for (int s = 0; s < 2; s++) {
            int kb = s * 32 + ((lane >> 4) * 8);
            frag_ab af[4], bfr[4];
            #pragma unroll
            for (int m = 0; m < 4; m++) {
                int r = wm * 64 + m * 16 + (lane & 15);
                af[m] = *(const frag_ab*)((const char*)As + swz(r, kb));
            }
            #pragma unroll
            for (int n = 0; n < 4; n++) {
                int c = wn * 64 + n * 16 + (lane & 15);
                bfr[n] = *(const frag_ab*)((const char*)Bs + swz(c, kb));
            }
            #pragma unroll
            for (int m = 0; m < 4; m++)
                #pragma unroll
                for (int n = 0; n < 4; n++)
                    acc[m][n] = __builtin_amdgcn_mfma_f32_16x16x32_bf16(
                        af[m], bfr[n], acc[m][n], 0, 0, 0);
        }
    }

    #pragma unroll
    for (int m = 0; m < 4; m++) {
        int rl = wm * 64 + m * 16 + ((lane >> 4) * 4);
        #pragma unroll
        for (int j = 0; j < 4; j++) {
            float sc = sS[rl + j];
            size_t grow = (size_t)(row0 + rl + j);
            #pragma unroll
            for (int n = 0; n < 4; n++) {
                int gcol = col0 + wn * 64 + n * 16 + (lane & 15);
                Y[grow * 256 + gcol] = f2bf(acc[m][n][j] * sc);
            }
        }
    }
}

// ---------------- CSR gather aggregation: wave/node, shfl-broadcast indices ---
// Lane i preloads csr_src[start+i] (one wave-wide load); gathers issued 16-deep
// with ds_bpermute index broadcast -> no memory op on the gather critical path.
template <int MODE>
__global__ __launch_bounds__(256) void aggregate_kernel(
    const ushort_t* __restrict__ msg, const int* __restrict__ rp16,
    const int* __restrict__ csr_src,
    const float* __restrict__ bias, const float* __restrict__ gamma,
    const float* __restrict__ beta, void* __restrict__ outp)
{
    int wv = threadIdx.x >> 6, lane = threadIdx.x & 63;
    int n = blockIdx.x * 4 + wv;
    if (n >= NN) return;
    int start = rp16[n * SL];
    int end   = rp16[n * SL + SL];
    int cnt = end - start;
    float a0 = 0.f, a1 = 0.f, a2 = 0.f, a3 = 0.f;
    const uint2* base = (const uint2*)msg;

    for (int c0 = 0; c0 < cnt; c0 += 64) {
        int nc = cnt - c0; if (nc > 64) nc = 64;
        int ss = csr_src[start + c0 + ((lane < nc) ? lane : 0)];
        int i = 0;
        for (; i + 16 <= nc; i += 16) {
            uint2 v[16];
            #pragma unroll
            for (int j = 0; j < 16; j++) {
                int idx = __shfl(ss, i + j);
                v[j] = base[(size_t)idx * 64 + lane];
            }
            #pragma unroll
            for (int j = 0; j < 16; j++) {
                a0 += blo(v[j].x); a1 += bhi(v[j].x);
                a2 += blo(v[j].y); a3 += bhi(v[j].y);
            }
        }
        if (i + 8 <= nc) {
            uint2 v[8];
            #pragma unroll
            for (int j = 0; j < 8; j++) {
                int idx = __shfl(ss, i + j);
                v[j] = base[(size_t)idx * 64 + lane];
            }
            #pragma unroll
            for (int j = 0; j < 8; j++) {
                a0 += blo(v[j].x); a1 += bhi(v[j].x);
                a2 += blo(v[j].y); a3 += bhi(v[j].y);
            }
            i += 8;
        }
        if (i + 4 <= nc) {
            uint2 v[4];
            #pragma unroll
            for (int j = 0; j < 4; j++) {
                int idx = __shfl(ss, i + j);
                v[j] = base[(size_t)idx * 64 + lane];
            }
            #pragma unroll
            for (int j = 0; j < 4; j++) {
                a0 += blo(v[j].x); a1 += bhi(v[j].x);
                a2 += blo(v[j].y); a3 += bhi(v[j].y);
            }
            i += 4;
        }
        for (; i < nc; i++) {
            int idx = __shfl(ss, i);
            uint2 v = base[(size_t)idx * 64 + lane];
            a0 += blo(v.x); a1 += bhi(v.x); a2 += blo(v.y); a3 += bhi(v.y);
        }
    }

    float scl = rsqrtf((float)(cnt > 1 ? cnt : 1));
    float4 b = ((const float4*)bias)[lane];
    float r0 = a0 * scl + b.x;
    float r1 = a1 * scl + b.y;
    float r2 = a2 * scl + b.z;
    float r3 = a3 * scl + b.w;

    if (MODE == 0) {
        r0 = fmaxf(r0, 0.f); r1 = fmaxf(r1, 0.f);
        r2 = fmaxf(r2, 0.f); r3 = fmaxf(r3, 0.f);
        uint2 o;
        o.x = (uint_t)f2bf(r0) | ((uint_t)f2bf(r1) << 16);
        o.y = (uint_t)f2bf(r2) | ((uint_t)f2bf(r3) << 16);
        ((uint2*)outp)[(size_t)n * 64 + lane] = o;
    } else {
        float s1 = r0 + r1 + r2 + r3;
        #pragma unroll
        for (int off = 1; off < 64; off <<= 1) s1 += __shfl_xor(s1, off);
        float mu = s1 * (1.f / 256.f);
        float d0 = r0 - mu, d1 = r1 - mu, d2 = r2 - mu, d3 = r3 - mu;
        float s2 = d0 * d0 + d1 * d1 + d2 * d2 + d3 * d3;
        #pragma unroll
        for (int off = 1; off < 64; off <<= 1) s2 += __shfl_xor(s2, off);
        float rs = rsqrtf(s2 * (1.f / 256.f) + LN_EPS);
        float4 g  = ((const float4*)gamma)[lane];
        float4 be = ((const float4*)beta)[lane];
        float4 o;
        o.x = d0 * rs * g.x + be.x;
        o.y = d1 * rs * g.y + be.y;
        o.z = d2 * rs * g.z + be.z;
        o.w = d3 * rs * g.w + be.w;
        ((float4*)outp)[(size_t)n * 64 + lane] = o;
    }
}

extern "C" void kernel_launch(void* const* d_in, const int* in_sizes, int n_in,
                              void* d_out, int out_size, void* d_ws, size_t ws_size,
                              hipStream_t stream)
{
    const float* x     = (const float*)d_in[0];
    const float* W1    = (const float*)d_in[1];
    const float* b1    = (const float*)d_in[2];
    const float* W2    = (const float*)d_in[3];
    const float* b2    = (const float*)d_in[4];
    const float* gamma = (const float*)d_in[5];
    const float* beta  = (const float*)d_in[6];
    const int*   src   = (const int*)d_in[7];
    const int*   dst   = (const int*)d_in[8];
    float* out = (float*)d_out;

    // ws layout (~55 MB)
    uint2*    dpart  = (uint2*)d_ws;                         // EE uint2   12.8MB
    ushort_t* msg    = (ushort_t*)(dpart + EE);              // MPAD*256   25.6MB
    int*      csr    = (int*)(msg + (size_t)MPAD * 256);     // EE          6.4MB
    int*      spart  = csr + EE;                             // EE          6.4MB
    int*      rp16   = spart + EE;                           // NB*FB+16    3.2MB
    int*      cntD   = rp16 + NB * FB + 16;
    int*      cntS   = cntD + NB * NBLK;
    int*      scanD  = cntS + NB * NBLK;
    int*      scanS  = scanD + NB * NBLK;
    int*      bbD    = scanS + NB * NBLK;                    // 320 (257 used)
    int*      bbS    = bbD + 320;                            // 320
    int*      degout = bbS + 320;                            // 50176
    ushort_t* Wt1    = (ushort_t*)(degout + NB * BR);        // 65536 bf16
    ushort_t* Wt2    = Wt1 + 65536;                          // 65536 bf16

    ushort_t* h = (ushort_t*)d_out;   // layer-1 activation (bf16) in d_out

    radix_count  <<<NBLK, 256, 0, stream>>>(src, dst, cntD, cntS);
    radix_scan   <<<2, 256, 0, stream>>>(cntD, scanD, bbD, cntS, scanS, bbS);
    radix_scatter<<<NBLK, 256, 0, stream>>>(src, dst, scanD, scanS, dpart, spart);
    fine_dst     <<<NB, 256, 0, stream>>>(dpart, bbD, rp16, csr);
    fine_src     <<<NB, 256, 0, stream>>>(spart, bbS, degout);

    wconv<<<256, 256, 0, stream>>>(W1, Wt1);
    wconv<<<256, 256, 0, stream>>>(W2, Wt2);

    dim3 gg(MPAD / 128, 2);
    gemm_mfma<0><<<gg, 256, 0, stream>>>(x, Wt1, degout, msg);
    aggregate_kernel<0><<<(NN + 3) / 4, 256, 0, stream>>>(msg, rp16, csr,
                                                          b1, nullptr, nullptr, h);
    gemm_mfma<1><<<gg, 256, 0, stream>>>(h, Wt2, degout, msg);
    aggregate_kernel<1><<<(NN + 3) / 4, 256, 0, stream>>>(msg, rp16, csr,
                                                          b2, gamma, beta, out);
}